// Round 10
// baseline (149.236 us; speedup 1.0000x reference)
//
#include <hip/hip_runtime.h>

#define NQ 6
#define HID 32
#define SNAPS 16
#define BATCH 1024
#define FSTRIDE 24       // floats per feature vector
#define FTOT 384         // 16 * 24
#define KSTR 24          // K-matrix LDS stride (16B-aligned, <=2-way conflicts = free)
#define KF   192         // per-f block: 8 cols/rows x 24

typedef float v2f __attribute__((ext_vector_type(2)));     // -> v_pk_fma_f32
typedef float vfloat4 __attribute__((ext_vector_type(4))); // nontemporal stores

__device__ __forceinline__ float sigm_f(float x) { return 1.0f / (1.0f + __expf(-x)); }
__device__ __forceinline__ float tanh_f(float x) { return 1.0f - 2.0f / (__expf(2.0f * x) + 1.0f); }

__device__ __forceinline__ void rc_entry(float g, float b0, float b1, float b2,
                                         int i, int j, float& re, float& im) {
    // rc = (I + 3*shadow*B)/2, B = b0*sx + b1*sy + b2*sz ; g = 1.5*shadow
    if (i == j) { re = 0.5f + (i ? -g * b2 : g * b2); im = 0.0f; }
    else        { re = g * b0;  im = (i ? g * b1 : -g * b1); }
}

// One block per batch element.
// Phase 1: WAVE 0 ONLY runs the whole 15-step LSTM chain (lane l owns gate
//   rows l and l+64 in VGPRs; activation via shfl_xor; Wp in LDS). Zero block
//   barriers inside the chain — waves 1-3 park at barrier #2. [R9: P1=23us was
//   dominated by 30 block barriers + cross-wave sg round-trips.]
// Phase 2: all 4 waves build KA/KB (R6-verified layout) and accumulate with
//   packed-fp32 complex MACs (R8-verified).
__global__ __launch_bounds__(256, 1)   // no VGPR cap: wave-0 chain holds ~150 live regs
void fused_kernel(const float* __restrict__ snapshot,   // (B,6)
                  const float* __restrict__ bcv,        // (B,6,3)
                  const float* __restrict__ h0,         // (B,32)
                  const float* __restrict__ c0,         // (B,32)
                  const float* __restrict__ W_ih,       // (128,24)
                  const float* __restrict__ W_hh,       // (128,32)
                  const float* __restrict__ b_ih,       // (128)
                  const float* __restrict__ b_hh,       // (128)
                  const float* __restrict__ Wp,         // (6,32,3)
                  const float* __restrict__ bp,         // (6,3)
                  float* __restrict__ out,              // (B,2,64,64)
                  float* __restrict__ out_tail)         // (B,6,3)
{
    __shared__ __align__(16) float sKA[16 * KF];   // 3072
    __shared__ __align__(16) float sKB[16 * KF];   // 3072
    __shared__ __align__(16) float feat[FTOT];     // 384
    __shared__ __align__(16) float sh[HID];        // 32
    __shared__ __align__(16) float sWpT[18 * 36];  // WpT[(3q+s)][h], padded stride 36
    __shared__ float sbp[18];

    const int b = blockIdx.x;
    const int t = threadIdx.x;

    // ---- preamble (all waves): Wp -> LDS transposed ----
    for (int idx = t; idx < NQ * HID * 3; idx += 256) {
        int q = idx / 96, r = idx - q * 96;
        int h = r / 3, s = r - h * 3;
        sWpT[(q * 3 + s) * 36 + h] = Wp[idx];
    }
    if (t >= 64 && t < 82) sbp[t - 64] = bp[t - 64];

    // ---- wave-0 chain state: rows l (i|f) and l+64 (g|o) in VGPRs ----
    float4 wih0[6], wih1[6], whh0[8], whh1[8];
    float bias0 = 0.0f, bias1 = 0.0f, c = 0.0f;
    if (t < 64) {
        const float4* p0 = (const float4*)(W_ih + t * 24);
        const float4* p1 = (const float4*)(W_ih + (t + 64) * 24);
        #pragma unroll
        for (int k = 0; k < 6; ++k) { wih0[k] = p0[k]; wih1[k] = p1[k]; }
        const float4* q0 = (const float4*)(W_hh + t * 32);
        const float4* q1 = (const float4*)(W_hh + (t + 64) * 32);
        #pragma unroll
        for (int k = 0; k < 8; ++k) { whh0[k] = q0[k]; whh1[k] = q1[k]; }
        bias0 = b_ih[t] + b_hh[t];
        bias1 = b_ih[t + 64] + b_hh[t + 64];
        if (t < 32) { c = c0[b * 32 + t]; sh[t] = h0[b * 32 + t]; }
        if (t < 24) feat[t] = (t < 6) ? snapshot[b * 6 + t] : bcv[b * 18 + (t - 6)];
    }
    __syncthreads();   // #1: sWpT/sbp/sh/feat ready

    // ---- LSTM chain: wave 0 only, no block barriers ----
    if (t < 64) {
        const int l = t;
        for (int step = 0; step < SNAPS - 1; ++step) {
            const float4* x4 = (const float4*)(feat + step * FSTRIDE);  // broadcast
            const float4* h4 = (const float4*)sh;
            float g0 = bias0, g1 = bias1, g0b = 0.0f, g1b = 0.0f;
            #pragma unroll
            for (int k = 0; k < 6; ++k) {
                float4 xq = x4[k];
                g0  += xq.x * wih0[k].x + xq.y * wih0[k].y;
                g0b += xq.z * wih0[k].z + xq.w * wih0[k].w;
                g1  += xq.x * wih1[k].x + xq.y * wih1[k].y;
                g1b += xq.z * wih1[k].z + xq.w * wih1[k].w;
            }
            #pragma unroll
            for (int k = 0; k < 8; ++k) {
                float4 hq = h4[k];
                g0  += hq.x * whh0[k].x + hq.y * whh0[k].y;
                g0b += hq.z * whh0[k].z + hq.w * whh0[k].w;
                g1  += hq.x * whh1[k].x + hq.y * whh1[k].y;
                g1b += hq.z * whh1[k].z + hq.w * whh1[k].w;
            }
            g0 += g0b; g1 += g1b;

            // lanes<32 hold (i,g); lanes>=32 hold (f,o)
            float gf = __shfl_xor(g0, 32);
            float go = __shfl_xor(g1, 32);
            if (l < 32) {
                c = sigm_f(gf) * c + sigm_f(g0) * tanh_f(g1);
                sh[l] = sigm_f(go) * tanh_f(c);
            }
            __builtin_amdgcn_wave_barrier();   // in-wave DS order: sh write -> reads

            // projection: lanes 0..17 read WpT row (float4) from LDS
            int rr = (l < 18) ? l : 17;
            const float4* wr  = (const float4*)&sWpT[rr * 36];
            const float4* h4b = (const float4*)sh;
            float la = (l < 18) ? sbp[rr] : 0.0f, lb = 0.0f;
            #pragma unroll
            for (int k = 0; k < 8; ++k) {
                float4 hq = h4b[k], wq = wr[k];
                la += hq.x * wq.x + hq.y * wq.y;
                lb += hq.z * wq.z + hq.w * wq.w;
            }
            float logit = la + lb;
            int q3 = 3 * (l < 6 ? l : 0);
            float l0 = __shfl(logit, q3), l1 = __shfl(logit, q3 + 1), l2 = __shfl(logit, q3 + 2);
            if (l < 6) {
                float m = fmaxf(l0, fmaxf(l1, l2));
                float e0 = __expf(l0 - m), e1 = __expf(l1 - m), e2 = __expf(l2 - m);
                float inv = 1.0f / (e0 + e1 + e2);
                float p0 = e0 * inv, p1 = e1 * inv, p2 = e2 * inv;
                float snap = p0 * p0 + p1 * p1 + p2 * p2;  // tr(M rho Mdag)=sum p^2 (rho unused)
                float* fd = feat + (step + 1) * FSTRIDE;
                fd[l] = snap;
                fd[6 + 3 * l]     = p0;
                fd[6 + 3 * l + 1] = p1;
                fd[6 + 3 * l + 2] = p2;
            }
            __builtin_amdgcn_wave_barrier();
        }
    }
    __syncthreads();   // #2: feat complete; waves 1-3 waited here

    // ---- tail output: bv of last feature = final probs ----
    if (t < 18) out_tail[b * 18 + t] = feat[15 * FSTRIDE + 6 + t];

    // ---- build KA/KB: 2048 entries, 8 per thread ----
    for (int n = t; n < 2048; n += 256) {
        int f = n >> 7, r = n & 127;
        int half = r >> 6, a = r & 63;
        const float* fx = &feat[f * FSTRIDE];
        int i0 = (a >> 5) & 1, i1 = (a >> 4) & 1, i2 = (a >> 3) & 1;
        int j0 = (a >> 2) & 1, j1 = (a >> 1) & 1, j2 = a & 1;
        int q = 3 * half;
        float g0 = 1.5f * fx[q], g1 = 1.5f * fx[q + 1], g2 = 1.5f * fx[q + 2];
        const float* bb = fx + 6 + 3 * q;
        float r0, m0, r1, m1, r2, m2;
        rc_entry(g0, bb[0], bb[1], bb[2], i0, j0, r0, m0);
        rc_entry(g1, bb[3], bb[4], bb[5], i1, j1, r1, m1);
        rc_entry(g2, bb[6], bb[7], bb[8], i2, j2, r2, m2);
        float pr = r0 * r1 - m0 * m1, pi = r0 * m1 + m0 * r1;
        float qr = pr * r2 - pi * m2, qi = pr * m2 + pi * r2;
        int row = a >> 3, col = a & 7;
        if (half == 0) {
            // KA: col-major, rows parity-grouped (even at [0..7], odd at [8..15])
            int off = f * KF + col * KSTR + ((row & 1) ? (7 + row) : row);
            sKA[off] = qr; sKA[off + 1] = qi;
        } else {
            int off = f * KF + row * KSTR + 2 * col;
            sKB[off] = qr; sKB[off + 1] = qi;
        }
    }
    __syncthreads();   // #3

    // ---- accumulate: out[i][j] = (1/16) sum_f KA[i>>3][j>>3]*KB[i&7][j&7]
    // i = v + 16k (k<4), j = 4u + d (d<4); packed complex MACs (v_pk_fma_f32)
    const int u = t & 15, v = t >> 4;
    const float* baseA = sKA + (u >> 1) * KSTR + 8 * (v >> 3);   // col jA, parity group
    const float* baseB = sKB + (v & 7) * KSTR + 8 * (u & 1);     // row iB, col group

    v2f acc[4][4];
    #pragma unroll
    for (int k = 0; k < 4; ++k)
        #pragma unroll
        for (int d = 0; d < 4; ++d) acc[k][d] = (v2f){0.0f, 0.0f};

    #pragma unroll 2
    for (int f = 0; f < SNAPS; ++f) {
        const v2f* A = (const v2f*)(baseA + f * KF);
        const v2f* B = (const v2f*)(baseB + f * KF);
        v2f a0 = A[0], a1 = A[1], a2 = A[2], a3 = A[3];
        v2f bq0 = B[0], bq1 = B[1], bq2 = B[2], bq3 = B[3];
        #define CMAC(k, a, d, b)                                   \
            acc[k][d] += (a).x * (b) + ((v2f){-(a).y, (a).y}) * (b).yx;
        #define CROW(k, a)  CMAC(k,a,0,bq0) CMAC(k,a,1,bq1) CMAC(k,a,2,bq2) CMAC(k,a,3,bq3)
        CROW(0, a0) CROW(1, a1) CROW(2, a2) CROW(3, a3)
        #undef CROW
        #undef CMAC
    }

    const float s = 1.0f / 16.0f;
    float* outb = out + (size_t)b * 8192;
    #pragma unroll
    for (int k = 0; k < 4; ++k) {
        int i = v + 16 * k;
        vfloat4 r4 = { acc[k][0].x * s, acc[k][1].x * s, acc[k][2].x * s, acc[k][3].x * s };
        vfloat4 i4 = { acc[k][0].y * s, acc[k][1].y * s, acc[k][2].y * s, acc[k][3].y * s };
        __builtin_nontemporal_store(r4, (vfloat4*)(outb + i * 64 + 4 * u));
        __builtin_nontemporal_store(i4, (vfloat4*)(outb + 4096 + i * 64 + 4 * u));
    }
}

extern "C" void kernel_launch(void* const* d_in, const int* in_sizes, int n_in,
                              void* d_out, int out_size, void* d_ws, size_t ws_size,
                              hipStream_t stream) {
    const float* snapshot = (const float*)d_in[0];
    const float* bcv      = (const float*)d_in[1];
    // d_in[2] = rho — unused: tr(M rho M^dag) = (sum_s p_s^2) tr(rho), tr(rho)=1
    const float* h0       = (const float*)d_in[3];
    const float* c0       = (const float*)d_in[4];
    const float* W_ih     = (const float*)d_in[5];
    const float* W_hh     = (const float*)d_in[6];
    const float* b_ih     = (const float*)d_in[7];
    const float* b_hh     = (const float*)d_in[8];
    const float* Wp       = (const float*)d_in[9];
    const float* bp       = (const float*)d_in[10];
    // d_in[11], d_in[12] = basis_r, basis_i — folded into rc_entry
    float* out = (float*)d_out;

    fused_kernel<<<BATCH, 256, 0, stream>>>(
        snapshot, bcv, h0, c0, W_ih, W_hh, b_ih, b_hh, Wp, bp,
        out, out + (size_t)BATCH * 8192);
}